// Round 1
// baseline (89.138 us; speedup 1.0000x reference)
//
#include <hip/hip_runtime.h>
#include <hip/hip_bf16.h>

// Problem constants
#define Bn 32
#define Nn 2048
#define Mn 12
#define FIN 64
#define FOUT 25
#define HPAD 28            // padded h row (floats) for float4 alignment
#define NBLK1 288          // 32 b * 3 groups * 3 chunks
#define NROWS 65536        // B*N
#define EPSBN 1e-5f

// ---------------------------------------------------------------------------
// K1: grouped linear + relu -> h[B][N][HPAD]; per-block BN partials (sum, sumsq)
// grid: 288 blocks (b, g, chunk), block 256. g is block-uniform -> scalar
// weight loads (SGPR), VALU does pure FMA.
// ---------------------------------------------------------------------------
__global__ __launch_bounds__(256) void k1_typelinear(
    const float* __restrict__ atom,      // [B][N][FIN]
    const float* __restrict__ type_w,    // [3][FIN][FOUT]
    const float* __restrict__ type_b,    // [3][FOUT]
    float* __restrict__ h,               // [B][N][HPAD]
    float* __restrict__ partials)        // [NBLK1][50]
{
    const int blk = blockIdx.x;
    const int b = blk / 9;
    const int rem = blk % 9;
    const int g = rem / 3;
    const int chunk = rem % 3;
    const int starts[4] = {0, 683, 1366, 2048};
    const int s0 = starts[g];
    const int e0 = starts[g + 1];
    const int tid = threadIdx.x;
    const int n = s0 + chunk * 256 + tid;
    const bool act = (n < e0);

    float acc[FOUT];

    if (act) {
        // load atom row into registers (16 x float4)
        float av[FIN];
        const float4* ap = reinterpret_cast<const float4*>(
            atom + ((size_t)b * Nn + n) * FIN);
        #pragma unroll
        for (int i = 0; i < FIN / 4; ++i) {
            float4 v = ap[i];
            av[4 * i + 0] = v.x; av[4 * i + 1] = v.y;
            av[4 * i + 2] = v.z; av[4 * i + 3] = v.w;
        }
        const float* wg = type_w + (size_t)g * (FIN * FOUT);
        const float* bg = type_b + (size_t)g * FOUT;
        #pragma unroll
        for (int o = 0; o < FOUT; ++o) acc[o] = bg[o];
        #pragma unroll
        for (int f = 0; f < FIN; ++f) {
            const float a = av[f];
            #pragma unroll
            for (int o = 0; o < FOUT; ++o)
                acc[o] += a * wg[f * FOUT + o];   // uniform idx -> s_load
        }
        #pragma unroll
        for (int o = 0; o < FOUT; ++o) acc[o] = fmaxf(acc[o], 0.0f);

        // store h row (25 floats: 6 x float4 + 1 scalar)
        float* hp = h + ((size_t)b * Nn + n) * HPAD;
        float4* hp4 = reinterpret_cast<float4*>(hp);
        #pragma unroll
        for (int i = 0; i < 6; ++i) {
            float4 v;
            v.x = acc[4 * i + 0]; v.y = acc[4 * i + 1];
            v.z = acc[4 * i + 2]; v.w = acc[4 * i + 3];
            hp4[i] = v;
        }
        hp[24] = acc[24];
    } else {
        #pragma unroll
        for (int o = 0; o < FOUT; ++o) acc[o] = 0.0f;
    }

    // block reduction of sum / sumsq per channel (fixed order, deterministic)
    __shared__ float red[256][51];   // 51 stride: conflict-free (gcd(19,32)=1)
    #pragma unroll
    for (int o = 0; o < FOUT; ++o) {
        red[tid][o] = acc[o];
        red[tid][FOUT + o] = acc[o] * acc[o];
    }
    __syncthreads();
    for (int s = 128; s > 0; s >>= 1) {
        if (tid < s) {
            #pragma unroll
            for (int c = 0; c < 50; ++c)
                red[tid][c] += red[tid + s][c];
        }
        __syncthreads();
    }
    if (tid < 50) partials[(size_t)blk * 50 + tid] = red[0][tid];
}

// ---------------------------------------------------------------------------
// K2: reduce partials -> per-channel affine A, C.  1 block, 64 threads.
// ---------------------------------------------------------------------------
__global__ void k2_bnstats(
    const float* __restrict__ partials,  // [NBLK1][50]
    const float* __restrict__ gamma,
    const float* __restrict__ beta,
    float* __restrict__ AC)              // [64]: A[0..24], C[25..49]
{
    const int o = threadIdx.x;
    if (o >= FOUT) return;
    float s1 = 0.0f, s2 = 0.0f;
    for (int p = 0; p < NBLK1; ++p) {
        s1 += partials[(size_t)p * 50 + o];
        s2 += partials[(size_t)p * 50 + FOUT + o];
    }
    const float inv_cnt = 1.0f / (float)NROWS;
    const float mean = s1 * inv_cnt;
    const float var = s2 * inv_cnt - mean * mean;
    const float a = gamma[o] * rsqrtf(var + EPSBN);
    AC[o] = a;
    AC[FOUT + o] = beta[o] - mean * a;
}

// ---------------------------------------------------------------------------
// K3: gather (BN applied on the fly) + conv linear + relu + out_w dot,
// block-level partial sum of the pooled dot product.
// grid: 256 blocks (b, chunk of 256 atoms), block 256.
// ---------------------------------------------------------------------------
__global__ __launch_bounds__(256) void k3_conv(
    const float* __restrict__ h,         // [B][N][HPAD]
    const float* __restrict__ bond,      // [B][N][M]
    const int*   __restrict__ adj,       // [B][N][M]
    const float* __restrict__ AC,        // [64]
    const float* __restrict__ conv_w,    // [FOUT][FOUT]
    const float* __restrict__ conv_b,    // [FOUT]
    const float* __restrict__ out_w,     // [FOUT][1]
    float* __restrict__ pe)              // [256] block partials
{
    const int blk = blockIdx.x;
    const int b = blk >> 3;
    const int chunk = blk & 7;
    const int tid = threadIdx.x;
    const int n = chunk * 256 + tid;

    // bond + adj rows (aligned: 12 elems * 4B = 48B)
    const float4* bp = reinterpret_cast<const float4*>(
        bond + ((size_t)b * Nn + n) * Mn);
    const int4* ajp = reinterpret_cast<const int4*>(
        adj + ((size_t)b * Nn + n) * Mn);
    float bw[Mn];
    int an[Mn];
    #pragma unroll
    for (int i = 0; i < 3; ++i) {
        float4 bv = bp[i];
        int4 av = ajp[i];
        bw[4 * i + 0] = bv.x; bw[4 * i + 1] = bv.y;
        bw[4 * i + 2] = bv.z; bw[4 * i + 3] = bv.w;
        an[4 * i + 0] = av.x; an[4 * i + 1] = av.y;
        an[4 * i + 2] = av.z; an[4 * i + 3] = av.w;
    }

    float msg[FOUT];
    #pragma unroll
    for (int f = 0; f < FOUT; ++f) msg[f] = 0.0f;
    float bsum = 0.0f;

    #pragma unroll
    for (int m = 0; m < Mn; ++m) {
        const float w = bw[m];
        bsum += w;
        const float4* hp = reinterpret_cast<const float4*>(
            h + ((size_t)b * Nn + an[m]) * HPAD);
        float hv[HPAD];
        #pragma unroll
        for (int i = 0; i < 7; ++i) {
            float4 v = hp[i];
            hv[4 * i + 0] = v.x; hv[4 * i + 1] = v.y;
            hv[4 * i + 2] = v.z; hv[4 * i + 3] = v.w;
        }
        #pragma unroll
        for (int f = 0; f < FOUT; ++f) msg[f] += w * hv[f];
    }

    // apply BN affine: msgn[f] = A[f]*msg[f] + C[f]*bsum   (uniform s_loads)
    float msgn[FOUT];
    #pragma unroll
    for (int f = 0; f < FOUT; ++f)
        msgn[f] = AC[f] * msg[f] + AC[FOUT + f] * bsum;

    // conv linear + relu + dot with out_w
    float v = 0.0f;
    #pragma unroll
    for (int o = 0; o < FOUT; ++o) {
        float t = conv_b[o];
        #pragma unroll
        for (int f = 0; f < FOUT; ++f)
            t += msgn[f] * conv_w[f * FOUT + o];
        t = fmaxf(t, 0.0f);
        v += t * out_w[o];
    }

    // block reduce v (fixed order: wave shuffle then 4-wave LDS)
    #pragma unroll
    for (int off = 32; off > 0; off >>= 1)
        v += __shfl_down(v, off, 64);
    __shared__ float wsum[4];
    const int wid = tid >> 6;
    const int lane = tid & 63;
    if (lane == 0) wsum[wid] = v;
    __syncthreads();
    if (tid == 0)
        pe[blk] = wsum[0] + wsum[1] + wsum[2] + wsum[3];
}

// ---------------------------------------------------------------------------
// K4: final per-batch reduce + relu.  1 block, 32 threads.
// ---------------------------------------------------------------------------
__global__ void k4_final(
    const float* __restrict__ pe,        // [256]
    const float* __restrict__ out_b,
    float* __restrict__ out)             // [B]
{
    const int b = threadIdx.x;
    if (b >= Bn) return;
    float s = 0.0f;
    #pragma unroll
    for (int c = 0; c < 8; ++c) s += pe[b * 8 + c];
    const float e = s * (1.0f / (float)Nn) + out_b[0];
    out[b] = fmaxf(e, 0.0f);
}

// ---------------------------------------------------------------------------
extern "C" void kernel_launch(void* const* d_in, const int* in_sizes, int n_in,
                              void* d_out, int out_size, void* d_ws, size_t ws_size,
                              hipStream_t stream)
{
    const float* atom   = (const float*)d_in[0];
    const float* bond   = (const float*)d_in[1];
    const int*   adjm   = (const int*)  d_in[2];
    const float* type_w = (const float*)d_in[3];
    const float* type_b = (const float*)d_in[4];
    const float* gamma  = (const float*)d_in[5];
    const float* beta   = (const float*)d_in[6];
    const float* conv_w = (const float*)d_in[7];
    const float* conv_b = (const float*)d_in[8];
    const float* out_w  = (const float*)d_in[9];
    const float* out_b  = (const float*)d_in[10];
    float* out = (float*)d_out;

    float* ws = (float*)d_ws;
    float* h        = ws;                         // B*N*HPAD = 1,835,008
    float* partials = h + (size_t)Bn * Nn * HPAD; // 288*50 = 14,400
    float* AC       = partials + NBLK1 * 50;      // 64
    float* pe       = AC + 64;                    // 256

    k1_typelinear<<<NBLK1, 256, 0, stream>>>(atom, type_w, type_b, h, partials);
    k2_bnstats<<<1, 64, 0, stream>>>(partials, gamma, beta, AC);
    k3_conv<<<256, 256, 0, stream>>>(h, bond, adjm, AC, conv_w, conv_b, out_w, pe);
    k4_final<<<1, 32, 0, stream>>>(pe, out_b, out);
}

// Round 2
// 78.875 us; speedup vs baseline: 1.1301x; 1.1301x over previous
//
#include <hip/hip_runtime.h>
#include <hip/hip_bf16.h>

// Problem constants
#define Bn 32
#define Nn 2048
#define Mn 12
#define FIN 64
#define FOUT 25
#define HPAD 28            // padded h row (floats) for float4 alignment
#define EPSBN 1e-5f

#define K1_BLOCKS 576      // 32 b * 3 groups * 6 chunks(128 atoms)
#define NPART (K1_BLOCKS * 4)   // per-wave partial rows = 2304
#define K3_BLOCKS 1024     // 32 chunks(64 atoms) * 32 b
#define NROWS 65536        // B*N

// ---------------------------------------------------------------------------
// K1: grouped linear + relu -> h[B][N][HPAD]; per-WAVE BN partials.
// 2 threads per atom (32 inputs each), pair-reduce via shfl_xor(1).
// BN partials: even lanes carry sum, odd lanes carry sumsq; 5-step butterfly
// over masks {2,4,8,16,32} reduces within lane-parity class. No LDS.
// ---------------------------------------------------------------------------
__global__ __launch_bounds__(256) void k1_typelinear(
    const float* __restrict__ atom,      // [B][N][FIN]
    const float* __restrict__ type_w,    // [3][FIN][FOUT]
    const float* __restrict__ type_b,    // [3][FOUT]
    float* __restrict__ h,               // [B][N][HPAD]
    float* __restrict__ partials)        // [NPART][50]
{
    const int blk = blockIdx.x;
    const int b = blk / 18;
    const int rem = blk % 18;
    const int g = rem / 6;
    const int chunk = rem % 6;
    const int starts[4] = {0, 683, 1366, 2048};
    const int s0 = starts[g];
    const int e0 = starts[g + 1];
    const int tid = threadIdx.x;
    const int a = tid >> 1;          // 0..127 atom within chunk
    const int half = tid & 1;        // which 32 input features
    const int n = s0 + chunk * 128 + a;
    const bool act = (n < e0);

    float acc[FOUT];
    #pragma unroll
    for (int o = 0; o < FOUT; ++o) acc[o] = 0.0f;

    if (act) {
        // load 32 input features (8 x float4), fully coalesced
        float av[32];
        const float4* ap = reinterpret_cast<const float4*>(
            atom + ((size_t)b * Nn + n) * FIN + half * 32);
        #pragma unroll
        for (int i = 0; i < 8; ++i) {
            float4 v = ap[i];
            av[4 * i + 0] = v.x; av[4 * i + 1] = v.y;
            av[4 * i + 2] = v.z; av[4 * i + 3] = v.w;
        }
        const float* wg = type_w + (size_t)g * (FIN * FOUT) + half * 32 * FOUT;
        #pragma unroll
        for (int f = 0; f < 32; ++f) {
            const float x = av[f];
            #pragma unroll
            for (int o = 0; o < FOUT; ++o)
                acc[o] = fmaf(x, wg[f * FOUT + o], acc[o]);  // uniform -> s_load
        }
    }

    // pair reduce (both lanes end with full pre-bias sum)
    #pragma unroll
    for (int o = 0; o < FOUT; ++o)
        acc[o] += __shfl_xor(acc[o], 1, 64);

    if (act) {
        const float* bg = type_b + (size_t)g * FOUT;
        #pragma unroll
        for (int o = 0; o < FOUT; ++o)
            acc[o] = fmaxf(acc[o] + bg[o], 0.0f);
        // store h row: half0 writes float4 0..2, half1 writes 3..5 + scalar
        float* hp = h + ((size_t)b * Nn + n) * HPAD;
        float4* hp4 = reinterpret_cast<float4*>(hp);
        if (half == 0) {
            #pragma unroll
            for (int i = 0; i < 3; ++i) {
                float4 v;
                v.x = acc[4 * i + 0]; v.y = acc[4 * i + 1];
                v.z = acc[4 * i + 2]; v.w = acc[4 * i + 3];
                hp4[i] = v;
            }
        } else {
            #pragma unroll
            for (int i = 3; i < 6; ++i) {
                float4 v;
                v.x = acc[4 * i + 0]; v.y = acc[4 * i + 1];
                v.z = acc[4 * i + 2]; v.w = acc[4 * i + 3];
                hp4[i] = v;
            }
            hp[24] = acc[24];
        }
    } else {
        #pragma unroll
        for (int o = 0; o < FOUT; ++o) acc[o] = 0.0f;
    }

    // BN partials: even lanes = sum, odd lanes = sumsq; butterfly masks 2..32
    const int lane = tid & 63;
    float s[FOUT];
    #pragma unroll
    for (int o = 0; o < FOUT; ++o) {
        float x = half ? acc[o] * acc[o] : acc[o];
        x += __shfl_xor(x, 2, 64);
        x += __shfl_xor(x, 4, 64);
        x += __shfl_xor(x, 8, 64);
        x += __shfl_xor(x, 16, 64);
        x += __shfl_xor(x, 32, 64);
        s[o] = x;
    }
    const int gw = blk * 4 + (tid >> 6);
    if (lane == 0) {
        #pragma unroll
        for (int o = 0; o < FOUT; ++o)
            partials[(size_t)gw * 50 + o] = s[o];
    } else if (lane == 1) {
        #pragma unroll
        for (int o = 0; o < FOUT; ++o)
            partials[(size_t)gw * 50 + FOUT + o] = s[o];
    }
}

// ---------------------------------------------------------------------------
// K2: reduce per-wave partials -> per-channel affine A, C.
// 25 blocks (one channel pair each) x 64 threads, butterfly reduce.
// ---------------------------------------------------------------------------
__global__ void k2_bnstats(
    const float* __restrict__ partials,  // [NPART][50]
    const float* __restrict__ gamma,
    const float* __restrict__ beta,
    float* __restrict__ AC)              // [50]: A[0..24], C[25..49]
{
    const int c = blockIdx.x;            // channel 0..24
    const int lane = threadIdx.x;        // 64
    float s1 = 0.0f, s2 = 0.0f;
    for (int p = lane; p < NPART; p += 64) {
        s1 += partials[(size_t)p * 50 + c];
        s2 += partials[(size_t)p * 50 + FOUT + c];
    }
    #pragma unroll
    for (int m = 1; m < 64; m <<= 1) {
        s1 += __shfl_xor(s1, m, 64);
        s2 += __shfl_xor(s2, m, 64);
    }
    if (lane == 0) {
        const float inv_cnt = 1.0f / (float)NROWS;
        const float mean = s1 * inv_cnt;
        const float var = s2 * inv_cnt - mean * mean;
        const float a = gamma[c] * rsqrtf(var + EPSBN);
        AC[c] = a;
        AC[FOUT + c] = beta[c] - mean * a;
    }
}

// ---------------------------------------------------------------------------
// K3: gather + BN-on-the-fly + conv linear + relu + out_w dot.
// 4 threads per atom (3 neighbors each), 64 atoms/block, 1024 blocks.
// XCD locality: b = blk & 31 -> blk%8 == b%8, all 32 blocks of a batch on
// one XCD; 4 batch h-slabs (4 x 229 KB) stay L2-resident.
// ---------------------------------------------------------------------------
__global__ __launch_bounds__(256) void k3_conv(
    const float* __restrict__ h,         // [B][N][HPAD]
    const float* __restrict__ bond,      // [B][N][M]
    const int*   __restrict__ adj,       // [B][N][M]
    const float* __restrict__ AC,        // [50]
    const float* __restrict__ conv_w,    // [FOUT][FOUT]
    const float* __restrict__ conv_b,    // [FOUT]
    const float* __restrict__ out_w,     // [FOUT][1]
    float* __restrict__ pe)              // [K3_BLOCKS] block partials
{
    const int blk = blockIdx.x;
    const int b = blk & 31;
    const int chunk = blk >> 5;
    const int tid = threadIdx.x;
    const int a = tid >> 2;              // atom within chunk (0..63)
    const int mg = tid & 3;              // neighbor group (3 each)
    const int n = chunk * 64 + a;
    const size_t row = (size_t)b * Nn + n;

    // 3 bond weights + 3 neighbor indices (coalesced scalar loads)
    const float* bp = bond + row * Mn + mg * 3;
    const int*   ajp = adj + row * Mn + mg * 3;
    const float w0 = bp[0], w1 = bp[1], w2 = bp[2];
    const int a0 = ajp[0], a1 = ajp[1], a2 = ajp[2];
    float bsum = w0 + w1 + w2;

    const float* hb = h + (size_t)b * Nn * HPAD;
    const float4* p0 = reinterpret_cast<const float4*>(hb + (size_t)a0 * HPAD);
    const float4* p1 = reinterpret_cast<const float4*>(hb + (size_t)a1 * HPAD);
    const float4* p2 = reinterpret_cast<const float4*>(hb + (size_t)a2 * HPAD);

    float hv0[HPAD], hv1[HPAD];
    #pragma unroll
    for (int i = 0; i < 7; ++i) {
        float4 v = p0[i];
        hv0[4 * i + 0] = v.x; hv0[4 * i + 1] = v.y;
        hv0[4 * i + 2] = v.z; hv0[4 * i + 3] = v.w;
    }
    #pragma unroll
    for (int i = 0; i < 7; ++i) {
        float4 v = p1[i];
        hv1[4 * i + 0] = v.x; hv1[4 * i + 1] = v.y;
        hv1[4 * i + 2] = v.z; hv1[4 * i + 3] = v.w;
    }
    float msg[FOUT];
    #pragma unroll
    for (int f = 0; f < FOUT; ++f) msg[f] = w0 * hv0[f];
    #pragma unroll
    for (int i = 0; i < 7; ++i) {        // reuse hv0 regs for row 2
        float4 v = p2[i];
        hv0[4 * i + 0] = v.x; hv0[4 * i + 1] = v.y;
        hv0[4 * i + 2] = v.z; hv0[4 * i + 3] = v.w;
    }
    #pragma unroll
    for (int f = 0; f < FOUT; ++f) msg[f] = fmaf(w1, hv1[f], msg[f]);
    #pragma unroll
    for (int f = 0; f < FOUT; ++f) msg[f] = fmaf(w2, hv0[f], msg[f]);

    // reduce the 4 lanes of this atom (width-4 butterfly)
    #pragma unroll
    for (int f = 0; f < FOUT; ++f) {
        msg[f] += __shfl_xor(msg[f], 1, 64);
        msg[f] += __shfl_xor(msg[f], 2, 64);
    }
    bsum += __shfl_xor(bsum, 1, 64);
    bsum += __shfl_xor(bsum, 2, 64);

    // BN affine on the fly
    float msgn[FOUT];
    #pragma unroll
    for (int f = 0; f < FOUT; ++f)
        msgn[f] = AC[f] * msg[f] + AC[FOUT + f] * bsum;

    // conv outputs split across the 4 lanes: o = 4k + mg
    float v = 0.0f;
    #pragma unroll
    for (int k = 0; k < 7; ++k) {
        const int o = 4 * k + mg;
        if (o < FOUT) {
            float t = conv_b[o];
            #pragma unroll
            for (int f = 0; f < FOUT; ++f)
                t = fmaf(msgn[f], conv_w[f * FOUT + o], t);
            v += fmaxf(t, 0.0f) * out_w[o];
        }
    }

    // wave butterfly (sums 16 atoms x 4 lane-partials), then 4-wave LDS
    #pragma unroll
    for (int m = 1; m < 64; m <<= 1)
        v += __shfl_xor(v, m, 64);
    __shared__ float wsum[4];
    const int wid = tid >> 6;
    if ((tid & 63) == 0) wsum[wid] = v;
    __syncthreads();
    if (tid == 0)
        pe[blk] = wsum[0] + wsum[1] + wsum[2] + wsum[3];
}

// ---------------------------------------------------------------------------
// K4: final per-batch reduce + relu.  1 block, 32 threads.
// ---------------------------------------------------------------------------
__global__ void k4_final(
    const float* __restrict__ pe,        // [K3_BLOCKS], blk = chunk*32 + b
    const float* __restrict__ out_b,
    float* __restrict__ out)             // [B]
{
    const int b = threadIdx.x;
    if (b >= Bn) return;
    float s = 0.0f;
    #pragma unroll
    for (int c = 0; c < 32; ++c) s += pe[c * 32 + b];
    const float e = s * (1.0f / (float)Nn) + out_b[0];
    out[b] = fmaxf(e, 0.0f);
}

// ---------------------------------------------------------------------------
extern "C" void kernel_launch(void* const* d_in, const int* in_sizes, int n_in,
                              void* d_out, int out_size, void* d_ws, size_t ws_size,
                              hipStream_t stream)
{
    const float* atom   = (const float*)d_in[0];
    const float* bond   = (const float*)d_in[1];
    const int*   adjm   = (const int*)  d_in[2];
    const float* type_w = (const float*)d_in[3];
    const float* type_b = (const float*)d_in[4];
    const float* gamma  = (const float*)d_in[5];
    const float* beta   = (const float*)d_in[6];
    const float* conv_w = (const float*)d_in[7];
    const float* conv_b = (const float*)d_in[8];
    const float* out_w  = (const float*)d_in[9];
    const float* out_b  = (const float*)d_in[10];
    float* out = (float*)d_out;

    float* ws = (float*)d_ws;
    float* h        = ws;                         // B*N*HPAD = 1,835,008
    float* partials = h + (size_t)Bn * Nn * HPAD; // NPART*50 = 115,200
    float* AC       = partials + (size_t)NPART * 50;  // 50
    float* pe       = AC + 50;                    // 1024

    k1_typelinear<<<K1_BLOCKS, 256, 0, stream>>>(atom, type_w, type_b, h, partials);
    k2_bnstats<<<FOUT, 64, 0, stream>>>(partials, gamma, beta, AC);
    k3_conv<<<K3_BLOCKS, 256, 0, stream>>>(h, bond, adjm, AC, conv_w, conv_b, out_w, pe);
    k4_final<<<1, 32, 0, stream>>>(pe, out_b, out);
}

// Round 3
// 49.224 us; speedup vs baseline: 1.8109x; 1.6024x over previous
//
#include <hip/hip_runtime.h>
#include <hip/hip_bf16.h>

// Problem constants
#define Bn 32
#define Nn 2048
#define Mn 12
#define FIN 64
#define FOUT 25
#define HPAD 28            // padded h row (floats) for float4 alignment
#define EPSBN 1e-5f

#define K1_BLOCKS 576      // 32 b * 3 groups * 6 chunks(128 atoms)
#define NPART (K1_BLOCKS * 2 * 4)   // per-16-lane partial rows = 4608
#define K3_BLOCKS 1024     // 32 chunks(64 atoms) * 32 b
#define NROWS 65536        // B*N

// ---------------------------------------------------------------------------
// K1: grouped linear + relu -> h[B][N][HPAD]; BN partials per 16-lane group.
// 1 thread per atom: weight indices are (block-uniform g) x (compile-time
// f,o) -> compiler emits s_loads, VALU is pure v_fmac. No LDS, no barriers.
// Partials: butterfly masks {1,2,4,8}; lane (lane&15)==0 of each 16-group
// writes one row of psum/psq (transposed [FOUT][NPART] for coalesced k2).
// ---------------------------------------------------------------------------
__global__ __launch_bounds__(128) void k1_typelinear(
    const float* __restrict__ atom,      // [B][N][FIN]
    const float* __restrict__ type_w,    // [3][FIN][FOUT]
    const float* __restrict__ type_b,    // [3][FOUT]
    float* __restrict__ h,               // [B][N][HPAD]
    float* __restrict__ psum,            // [FOUT][NPART]
    float* __restrict__ psq)             // [FOUT][NPART]
{
    const int blk = blockIdx.x;
    const int b = blk / 18;
    const int rem = blk % 18;
    const int g = rem / 6;
    const int chunk = rem % 6;
    const int starts[4] = {0, 683, 1366, 2048};
    const int s0 = starts[g];
    const int e0 = starts[g + 1];
    const int tid = threadIdx.x;         // 0..127
    const int n = s0 + chunk * 128 + tid;
    const bool act = (n < e0);

    float acc[FOUT];
    #pragma unroll
    for (int o = 0; o < FOUT; ++o) acc[o] = 0.0f;

    if (act) {
        // full atom row: 16 x float4, contiguous 256B per thread
        float av[FIN];
        const float4* ap = reinterpret_cast<const float4*>(
            atom + ((size_t)b * Nn + n) * FIN);
        #pragma unroll
        for (int i = 0; i < FIN / 4; ++i) {
            float4 v = ap[i];
            av[4 * i + 0] = v.x; av[4 * i + 1] = v.y;
            av[4 * i + 2] = v.z; av[4 * i + 3] = v.w;
        }
        const float* wg = type_w + (size_t)g * (FIN * FOUT);
        #pragma unroll
        for (int f = 0; f < FIN; ++f) {
            const float x = av[f];
            #pragma unroll
            for (int o = 0; o < FOUT; ++o)
                acc[o] = fmaf(x, wg[f * FOUT + o], acc[o]);  // s_load weights
        }
        const float* bg = type_b + (size_t)g * FOUT;
        #pragma unroll
        for (int o = 0; o < FOUT; ++o)
            acc[o] = fmaxf(acc[o] + bg[o], 0.0f);

        // store h row: 6 x float4 + scalar
        float* hp = h + ((size_t)b * Nn + n) * HPAD;
        float4* hp4 = reinterpret_cast<float4*>(hp);
        #pragma unroll
        for (int i = 0; i < 6; ++i) {
            float4 v;
            v.x = acc[4 * i + 0]; v.y = acc[4 * i + 1];
            v.z = acc[4 * i + 2]; v.w = acc[4 * i + 3];
            hp4[i] = v;
        }
        hp[24] = acc[24];
    }

    // BN partials: butterfly masks {1,2,4,8} -> 16-lane group sums
    const int lane = tid & 63;
    float bs[FOUT], bq[FOUT];
    #pragma unroll
    for (int o = 0; o < FOUT; ++o) {
        float s = acc[o];
        float q = acc[o] * acc[o];
        s += __shfl_xor(s, 1, 64);  q += __shfl_xor(q, 1, 64);
        s += __shfl_xor(s, 2, 64);  q += __shfl_xor(q, 2, 64);
        s += __shfl_xor(s, 4, 64);  q += __shfl_xor(q, 4, 64);
        s += __shfl_xor(s, 8, 64);  q += __shfl_xor(q, 8, 64);
        bs[o] = s; bq[o] = q;
    }
    const int row = (blk * 2 + (tid >> 6)) * 4 + (lane >> 4);
    if ((lane & 15) == 0) {
        #pragma unroll
        for (int o = 0; o < FOUT; ++o) {
            psum[(size_t)o * NPART + row] = bs[o];
            psq [(size_t)o * NPART + row] = bq[o];
        }
    }
}

// ---------------------------------------------------------------------------
// K2: reduce partials -> per-channel affine A, C.
// 25 blocks (one channel each) x 64 threads; fully coalesced float4 streams.
// ---------------------------------------------------------------------------
__global__ void k2_bnstats(
    const float* __restrict__ psum,      // [FOUT][NPART]
    const float* __restrict__ psq,       // [FOUT][NPART]
    const float* __restrict__ gamma,
    const float* __restrict__ beta,
    float* __restrict__ AC)              // [50]: A[0..24], C[25..49]
{
    const int c = blockIdx.x;            // channel 0..24
    const int lane = threadIdx.x;        // 64
    const float4* ps4 = reinterpret_cast<const float4*>(psum + (size_t)c * NPART);
    const float4* pq4 = reinterpret_cast<const float4*>(psq  + (size_t)c * NPART);
    float s1 = 0.0f, s2 = 0.0f;
    #pragma unroll 2
    for (int i = lane; i < NPART / 4; i += 64) {
        float4 v = ps4[i]; s1 += (v.x + v.y) + (v.z + v.w);
        float4 q = pq4[i]; s2 += (q.x + q.y) + (q.z + q.w);
    }
    #pragma unroll
    for (int m = 1; m < 64; m <<= 1) {
        s1 += __shfl_xor(s1, m, 64);
        s2 += __shfl_xor(s2, m, 64);
    }
    if (lane == 0) {
        const float inv_cnt = 1.0f / (float)NROWS;
        const float mean = s1 * inv_cnt;
        const float var = s2 * inv_cnt - mean * mean;
        const float a = gamma[c] * rsqrtf(var + EPSBN);
        AC[c] = a;
        AC[FOUT + c] = beta[c] - mean * a;
    }
}

// ---------------------------------------------------------------------------
// K3: gather + BN-on-the-fly + conv linear + relu + out_w dot.
// 4 threads per atom (3 neighbors each), 64 atoms/block, 1024 blocks.
// XCD locality: b = blk & 31 -> blk%8 == b%8, all 32 blocks of a batch on
// one XCD; 4 batch h-slabs (4 x 229 KB) stay L2-resident.
// ---------------------------------------------------------------------------
__global__ __launch_bounds__(256) void k3_conv(
    const float* __restrict__ h,         // [B][N][HPAD]
    const float* __restrict__ bond,      // [B][N][M]
    const int*   __restrict__ adj,       // [B][N][M]
    const float* __restrict__ AC,        // [50]
    const float* __restrict__ conv_w,    // [FOUT][FOUT]
    const float* __restrict__ conv_b,    // [FOUT]
    const float* __restrict__ out_w,     // [FOUT][1]
    float* __restrict__ pe)              // [K3_BLOCKS] block partials
{
    const int blk = blockIdx.x;
    const int b = blk & 31;
    const int chunk = blk >> 5;
    const int tid = threadIdx.x;
    const int a = tid >> 2;              // atom within chunk (0..63)
    const int mg = tid & 3;              // neighbor group (3 each)
    const int n = chunk * 64 + a;
    const size_t row = (size_t)b * Nn + n;

    // 3 bond weights + 3 neighbor indices (coalesced scalar loads)
    const float* bp = bond + row * Mn + mg * 3;
    const int*   ajp = adj + row * Mn + mg * 3;
    const float w0 = bp[0], w1 = bp[1], w2 = bp[2];
    const int a0 = ajp[0], a1 = ajp[1], a2 = ajp[2];
    float bsum = w0 + w1 + w2;

    const float* hb = h + (size_t)b * Nn * HPAD;
    const float4* p0 = reinterpret_cast<const float4*>(hb + (size_t)a0 * HPAD);
    const float4* p1 = reinterpret_cast<const float4*>(hb + (size_t)a1 * HPAD);
    const float4* p2 = reinterpret_cast<const float4*>(hb + (size_t)a2 * HPAD);

    float hv0[HPAD], hv1[HPAD];
    #pragma unroll
    for (int i = 0; i < 7; ++i) {
        float4 v = p0[i];
        hv0[4 * i + 0] = v.x; hv0[4 * i + 1] = v.y;
        hv0[4 * i + 2] = v.z; hv0[4 * i + 3] = v.w;
    }
    #pragma unroll
    for (int i = 0; i < 7; ++i) {
        float4 v = p1[i];
        hv1[4 * i + 0] = v.x; hv1[4 * i + 1] = v.y;
        hv1[4 * i + 2] = v.z; hv1[4 * i + 3] = v.w;
    }
    float msg[FOUT];
    #pragma unroll
    for (int f = 0; f < FOUT; ++f) msg[f] = w0 * hv0[f];
    #pragma unroll
    for (int i = 0; i < 7; ++i) {        // reuse hv0 regs for row 2
        float4 v = p2[i];
        hv0[4 * i + 0] = v.x; hv0[4 * i + 1] = v.y;
        hv0[4 * i + 2] = v.z; hv0[4 * i + 3] = v.w;
    }
    #pragma unroll
    for (int f = 0; f < FOUT; ++f) msg[f] = fmaf(w1, hv1[f], msg[f]);
    #pragma unroll
    for (int f = 0; f < FOUT; ++f) msg[f] = fmaf(w2, hv0[f], msg[f]);

    // reduce the 4 lanes of this atom (width-4 butterfly)
    #pragma unroll
    for (int f = 0; f < FOUT; ++f) {
        msg[f] += __shfl_xor(msg[f], 1, 64);
        msg[f] += __shfl_xor(msg[f], 2, 64);
    }
    bsum += __shfl_xor(bsum, 1, 64);
    bsum += __shfl_xor(bsum, 2, 64);

    // BN affine on the fly
    float msgn[FOUT];
    #pragma unroll
    for (int f = 0; f < FOUT; ++f)
        msgn[f] = AC[f] * msg[f] + AC[FOUT + f] * bsum;

    // conv outputs split across the 4 lanes: o = 4k + mg
    float v = 0.0f;
    #pragma unroll
    for (int k = 0; k < 7; ++k) {
        const int o = 4 * k + mg;
        if (o < FOUT) {
            float t = conv_b[o];
            #pragma unroll
            for (int f = 0; f < FOUT; ++f)
                t = fmaf(msgn[f], conv_w[f * FOUT + o], t);
            v += fmaxf(t, 0.0f) * out_w[o];
        }
    }

    // wave butterfly (sums 16 atoms x 4 lane-partials), then 4-wave LDS
    #pragma unroll
    for (int m = 1; m < 64; m <<= 1)
        v += __shfl_xor(v, m, 64);
    __shared__ float wsum[4];
    const int wid = tid >> 6;
    if ((tid & 63) == 0) wsum[wid] = v;
    __syncthreads();
    if (tid == 0)
        pe[blk] = wsum[0] + wsum[1] + wsum[2] + wsum[3];
}

// ---------------------------------------------------------------------------
// K4: final per-batch reduce + relu.  1 block, 32 threads.
// ---------------------------------------------------------------------------
__global__ void k4_final(
    const float* __restrict__ pe,        // [K3_BLOCKS], blk = chunk*32 + b
    const float* __restrict__ out_b,
    float* __restrict__ out)             // [B]
{
    const int b = threadIdx.x;
    if (b >= Bn) return;
    float s = 0.0f;
    #pragma unroll
    for (int c = 0; c < 32; ++c) s += pe[c * 32 + b];
    const float e = s * (1.0f / (float)Nn) + out_b[0];
    out[b] = fmaxf(e, 0.0f);
}

// ---------------------------------------------------------------------------
extern "C" void kernel_launch(void* const* d_in, const int* in_sizes, int n_in,
                              void* d_out, int out_size, void* d_ws, size_t ws_size,
                              hipStream_t stream)
{
    const float* atom   = (const float*)d_in[0];
    const float* bond   = (const float*)d_in[1];
    const int*   adjm   = (const int*)  d_in[2];
    const float* type_w = (const float*)d_in[3];
    const float* type_b = (const float*)d_in[4];
    const float* gamma  = (const float*)d_in[5];
    const float* beta   = (const float*)d_in[6];
    const float* conv_w = (const float*)d_in[7];
    const float* conv_b = (const float*)d_in[8];
    const float* out_w  = (const float*)d_in[9];
    const float* out_b  = (const float*)d_in[10];
    float* out = (float*)d_out;

    float* ws = (float*)d_ws;
    float* h    = ws;                             // B*N*HPAD = 1,835,008
    float* psum = h + (size_t)Bn * Nn * HPAD;     // FOUT*NPART = 115,200
    float* psq  = psum + (size_t)FOUT * NPART;    // 115,200
    float* AC   = psq + (size_t)FOUT * NPART;     // 50 (pad 64)
    float* pe   = AC + 64;                        // 1024

    k1_typelinear<<<K1_BLOCKS, 128, 0, stream>>>(atom, type_w, type_b, h, psum, psq);
    k2_bnstats<<<FOUT, 64, 0, stream>>>(psum, psq, gamma, beta, AC);
    k3_conv<<<K3_BLOCKS, 256, 0, stream>>>(h, bond, adjm, AC, conv_w, conv_b, out_w, pe);
    k4_final<<<1, 32, 0, stream>>>(pe, out_b, out);
}